// Round 2
// baseline (805.054 us; speedup 1.0000x reference)
//
#include <hip/hip_runtime.h>
#include <math.h>

#define NN 50000
#define EE 800000
#define EP 850000   // EE + NN self loops
#define DD 128
#define NEG_SLOPE 0.2f

// ---------------------------------------------------------------- histogram
__global__ void k_hist(const int* __restrict__ ei, int* __restrict__ counts) {
    int e = blockIdx.x * blockDim.x + threadIdx.x;
    if (e >= EP) return;
    int dst = (e < EE) ? ei[EE + e] : (e - EE);
    atomicAdd(&counts[dst], 1);
}

// ---------------------------------------------------------------- block scan
__global__ void k_scan1(const int* __restrict__ counts, int* __restrict__ row_ptr,
                        int* __restrict__ blockSums) {
    __shared__ int sm[1024];
    int t = threadIdx.x;
    int g = blockIdx.x * 1024 + t;
    int v = (g < NN) ? counts[g] : 0;
    sm[t] = v;
    __syncthreads();
    for (int off = 1; off < 1024; off <<= 1) {
        int add = (t >= off) ? sm[t - off] : 0;
        __syncthreads();
        sm[t] += add;
        __syncthreads();
    }
    if (g < NN) row_ptr[g] = sm[t] - v;   // exclusive
    if (t == 1023) blockSums[blockIdx.x] = sm[t];
}

__global__ void k_scan2(const int* __restrict__ blockSums, int* __restrict__ blockOffs,
                        int nb, int* __restrict__ row_ptr) {
    if (threadIdx.x == 0 && blockIdx.x == 0) {
        int run = 0;
        for (int i = 0; i < nb; ++i) { blockOffs[i] = run; run += blockSums[i]; }
        row_ptr[NN] = run;   // == EP
    }
}

__global__ void k_scan3(int* __restrict__ row_ptr, const int* __restrict__ blockOffs) {
    int g = blockIdx.x * 1024 + threadIdx.x;
    if (g < NN) row_ptr[g] += blockOffs[blockIdx.x];
}

// ---------------------------------------------------------------- scatter into CSR
__global__ void k_scatter(const int* __restrict__ ei, const float* __restrict__ eattr,
                          const int* __restrict__ row_ptr, int* __restrict__ fill,
                          int* __restrict__ src_sorted, float* __restrict__ ew_sorted) {
    int e = blockIdx.x * blockDim.x + threadIdx.x;
    if (e >= EP) return;
    int s, d; float w;
    if (e < EE) {
        s = ei[e]; d = ei[EE + e];
        float a = eattr[e];
        w = (a == 0.0f) ? 10000.0f : (1.0f / a);
    } else {
        s = d = e - EE;
        w = 0.0f;
    }
    int pos = row_ptr[d] + atomicAdd(&fill[d], 1);
    src_sorted[pos] = s;
    ew_sorted[pos] = w;
}

// ---------------------------------------------------------------- fused dual GEMM: xl = X@Wl, xr = X@Wr
// 32 rows/block, 256 threads, thread computes 4 rows x 4 cols for both W's.
#define GD_BM 32
__global__ __launch_bounds__(256) void k_gemm_dual(const float* __restrict__ X,
        const float* __restrict__ Wl, const float* __restrict__ Wr,
        float* __restrict__ xl, float* __restrict__ xr, int nrows) {
    __shared__ float xt[128][GD_BM + 4];   // [k][r], stride 36 floats (144B, 16B aligned)
    int t = threadIdx.x;
    int rowbase = blockIdx.x * GD_BM;

    {   // load + transpose x tile
        int r = t >> 5;            // 0..7
        int c0 = (t & 31) * 4;     // 0..124
        for (int rr = r; rr < GD_BM; rr += 8) {
            int gr = rowbase + rr;
            float4 v = make_float4(0.f, 0.f, 0.f, 0.f);
            if (gr < nrows) v = *(const float4*)&X[gr * DD + c0];
            xt[c0 + 0][rr] = v.x;
            xt[c0 + 1][rr] = v.y;
            xt[c0 + 2][rr] = v.z;
            xt[c0 + 3][rr] = v.w;
        }
    }
    __syncthreads();

    int r0 = (t >> 5) * 4;   // 0..28
    int c0 = (t & 31) * 4;   // 0..124
    float accL[4][4] = {{0}};
    float accR[4][4] = {{0}};

#pragma unroll 4
    for (int k = 0; k < 128; ++k) {
        float4 x4 = *(const float4*)&xt[k][r0];
        float4 wl = *(const float4*)&Wl[k * DD + c0];
        float4 wr = *(const float4*)&Wr[k * DD + c0];
        float xs[4] = {x4.x, x4.y, x4.z, x4.w};
        float wls[4] = {wl.x, wl.y, wl.z, wl.w};
        float wrs[4] = {wr.x, wr.y, wr.z, wr.w};
#pragma unroll
        for (int i = 0; i < 4; ++i)
#pragma unroll
            for (int j = 0; j < 4; ++j) {
                accL[i][j] = fmaf(xs[i], wls[j], accL[i][j]);
                accR[i][j] = fmaf(xs[i], wrs[j], accR[i][j]);
            }
    }

#pragma unroll
    for (int i = 0; i < 4; ++i) {
        int row = rowbase + r0 + i;
        if (row < nrows) {
            float4 vL = make_float4(accL[i][0], accL[i][1], accL[i][2], accL[i][3]);
            float4 vR = make_float4(accR[i][0], accR[i][1], accR[i][2], accR[i][3]);
            *(float4*)&xl[row * DD + c0] = vL;
            *(float4*)&xr[row * DD + c0] = vR;
        }
    }
}

// ---------------------------------------------------------------- aggregation: wave per node, online softmax
__global__ __launch_bounds__(256) void k_agg(const float* __restrict__ xl,
        const float* __restrict__ xr, const int* __restrict__ row_ptr,
        const int* __restrict__ src_sorted, const float* __restrict__ ew_sorted,
        const float* __restrict__ We, const float* __restrict__ att,
        const float* __restrict__ bias, float* __restrict__ out, int do_relu) {
    int wid = (blockIdx.x * blockDim.x + threadIdx.x) >> 6;
    int lane = threadIdx.x & 63;
    if (wid >= NN) return;

    int c = lane * 2;
    float2 xrv = *(const float2*)&xr[wid * DD + c];
    float2 attv = *(const float2*)&att[c];
    float2 Wev = *(const float2*)&We[c];

    int beg = row_ptr[wid];
    int end = row_ptr[wid + 1];

    float m = -INFINITY;
    float denom = 0.0f;
    float acc0 = 0.0f, acc1 = 0.0f;

    for (int e = beg; e < end; ++e) {
        int s = src_sorted[e];
        float w = ew_sorted[e];
        float2 xls = *(const float2*)&xl[s * DD + c];
        float t0 = xls.x + xrv.x + w * Wev.x;
        float t1 = xls.y + xrv.y + w * Wev.y;
        t0 = (t0 > 0.0f) ? t0 : NEG_SLOPE * t0;
        t1 = (t1 > 0.0f) ? t1 : NEG_SLOPE * t1;
        float p = t0 * attv.x + t1 * attv.y;
#pragma unroll
        for (int o = 32; o >= 1; o >>= 1) p += __shfl_xor(p, o, 64);
        float logit = p;
        float nm = fmaxf(m, logit);
        float so = __expf(m - nm);       // exp(-inf) = 0 on first edge
        float pe = __expf(logit - nm);
        denom = denom * so + pe;
        acc0 = acc0 * so + pe * xls.x;
        acc1 = acc1 * so + pe * xls.y;
        m = nm;
    }

    float inv = 1.0f / denom;
    float o0 = acc0 * inv + bias[c];
    float o1 = acc1 * inv + bias[c + 1];
    if (do_relu) { o0 = fmaxf(o0, 0.0f); o1 = fmaxf(o1, 0.0f); }
    float2 ov = make_float2(o0, o1);
    *(float2*)&out[wid * DD + c] = ov;
}

// ---------------------------------------------------------------- final linear: out[i] = h[i] . Wlin + blin
__global__ __launch_bounds__(256) void k_final(const float* __restrict__ h,
        const float* __restrict__ Wlin, const float* __restrict__ blin,
        float* __restrict__ out) {
    int wid = (blockIdx.x * blockDim.x + threadIdx.x) >> 6;
    int lane = threadIdx.x & 63;
    if (wid >= NN) return;
    float2 hv = *(const float2*)&h[wid * DD + lane * 2];
    float2 wv = *(const float2*)&Wlin[lane * 2];
    float p = hv.x * wv.x + hv.y * wv.y;
#pragma unroll
    for (int o = 32; o >= 1; o >>= 1) p += __shfl_xor(p, o, 64);
    if (lane == 0) out[wid] = p + blin[0];
}

// ----------------------------------------------------------------
static inline size_t align256(size_t x) { return (x + 255) & ~(size_t)255; }

extern "C" void kernel_launch(void* const* d_in, const int* in_sizes, int n_in,
                              void* d_out, int out_size, void* d_ws, size_t ws_size,
                              hipStream_t stream) {
    const float* x     = (const float*)d_in[0];
    const int*   ei    = (const int*)d_in[1];
    const float* eattr = (const float*)d_in[2];
    const float* Wl[3]  = {(const float*)d_in[3],  (const float*)d_in[8],  (const float*)d_in[13]};
    const float* Wr[3]  = {(const float*)d_in[4],  (const float*)d_in[9],  (const float*)d_in[14]};
    const float* We[3]  = {(const float*)d_in[5],  (const float*)d_in[10], (const float*)d_in[15]};
    const float* att[3] = {(const float*)d_in[6],  (const float*)d_in[11], (const float*)d_in[16]};
    const float* bb[3]  = {(const float*)d_in[7],  (const float*)d_in[12], (const float*)d_in[17]};
    const float* Wlin = (const float*)d_in[18];
    const float* blin = (const float*)d_in[19];

    char* p = (char*)d_ws;
    int* counts = (int*)p;          p += align256((size_t)NN * 4);
    int* fill   = (int*)p;          p += align256((size_t)NN * 4);
    int* row_ptr= (int*)p;          p += align256((size_t)(NN + 1) * 4);
    int* blockSums = (int*)p;       p += align256(64 * 4);
    int* blockOffs = (int*)p;       p += align256(64 * 4);
    int* src_sorted = (int*)p;      p += align256((size_t)EP * 4);
    float* ew_sorted = (float*)p;   p += align256((size_t)EP * 4);
    float* xl = (float*)p;          p += align256((size_t)NN * DD * 4);
    float* xr = (float*)p;          p += align256((size_t)NN * DD * 4);
    float* hA = (float*)p;          p += align256((size_t)NN * DD * 4);
    float* hB = (float*)p;          p += align256((size_t)NN * DD * 4);

    // zero counts + fill (adjacent allocations)
    hipMemsetAsync(counts, 0, align256((size_t)NN * 4) + align256((size_t)NN * 4), stream);

    const int nb_scan = (NN + 1023) / 1024;   // 49
    k_hist<<<(EP + 255) / 256, 256, 0, stream>>>(ei, counts);
    k_scan1<<<nb_scan, 1024, 0, stream>>>(counts, row_ptr, blockSums);
    k_scan2<<<1, 64, 0, stream>>>(blockSums, blockOffs, nb_scan, row_ptr);
    k_scan3<<<nb_scan, 1024, 0, stream>>>(row_ptr, blockOffs);
    k_scatter<<<(EP + 255) / 256, 256, 0, stream>>>(ei, eattr, row_ptr, fill, src_sorted, ew_sorted);

    const int gemm_grid = (NN + GD_BM - 1) / GD_BM;
    const int agg_grid  = (NN + 3) / 4;       // 4 waves per 256-thread block

    // layer 1: x -> hA (relu)
    k_gemm_dual<<<gemm_grid, 256, 0, stream>>>(x, Wl[0], Wr[0], xl, xr, NN);
    k_agg<<<agg_grid, 256, 0, stream>>>(xl, xr, row_ptr, src_sorted, ew_sorted,
                                        We[0], att[0], bb[0], hA, 1);
    // layer 2: hA -> hB (relu)
    k_gemm_dual<<<gemm_grid, 256, 0, stream>>>(hA, Wl[1], Wr[1], xl, xr, NN);
    k_agg<<<agg_grid, 256, 0, stream>>>(xl, xr, row_ptr, src_sorted, ew_sorted,
                                        We[1], att[1], bb[1], hB, 1);
    // layer 3: hB -> hA (no relu)
    k_gemm_dual<<<gemm_grid, 256, 0, stream>>>(hB, Wl[2], Wr[2], xl, xr, NN);
    k_agg<<<agg_grid, 256, 0, stream>>>(xl, xr, row_ptr, src_sorted, ew_sorted,
                                        We[2], att[2], bb[2], hA, 0);

    k_final<<<agg_grid, 256, 0, stream>>>(hA, Wlin, blin, (float*)d_out);
}

// Round 3
// 647.363 us; speedup vs baseline: 1.2436x; 1.2436x over previous
//
#include <hip/hip_runtime.h>
#include <math.h>

#define NN 50000
#define EE 800000
#define EP 850000   // EE + NN self loops
#define DD 128
#define NEG_SLOPE 0.2f

typedef float f4 __attribute__((ext_vector_type(4)));

// ---------------------------------------------------------------- histogram
__global__ void k_hist(const int* __restrict__ ei, int* __restrict__ counts) {
    int e = blockIdx.x * blockDim.x + threadIdx.x;
    if (e >= EP) return;
    int dst = (e < EE) ? ei[EE + e] : (e - EE);
    atomicAdd(&counts[dst], 1);
}

// ---------------------------------------------------------------- block scan
__global__ void k_scan1(const int* __restrict__ counts, int* __restrict__ row_ptr,
                        int* __restrict__ blockSums) {
    __shared__ int sm[1024];
    int t = threadIdx.x;
    int g = blockIdx.x * 1024 + t;
    int v = (g < NN) ? counts[g] : 0;
    sm[t] = v;
    __syncthreads();
    for (int off = 1; off < 1024; off <<= 1) {
        int add = (t >= off) ? sm[t - off] : 0;
        __syncthreads();
        sm[t] += add;
        __syncthreads();
    }
    if (g < NN) row_ptr[g] = sm[t] - v;   // exclusive
    if (t == 1023) blockSums[blockIdx.x] = sm[t];
}

__global__ void k_scan2(const int* __restrict__ blockSums, int* __restrict__ blockOffs,
                        int nb, int* __restrict__ row_ptr) {
    if (threadIdx.x == 0 && blockIdx.x == 0) {
        int run = 0;
        for (int i = 0; i < nb; ++i) { blockOffs[i] = run; run += blockSums[i]; }
        row_ptr[NN] = run;   // == EP
    }
}

__global__ void k_scan3(int* __restrict__ row_ptr, const int* __restrict__ blockOffs) {
    int g = blockIdx.x * 1024 + threadIdx.x;
    if (g < NN) row_ptr[g] += blockOffs[blockIdx.x];
}

// ---------------------------------------------------------------- scatter into CSR
__global__ void k_scatter(const int* __restrict__ ei, const float* __restrict__ eattr,
                          const int* __restrict__ row_ptr, int* __restrict__ fill,
                          int* __restrict__ src_sorted, float* __restrict__ ew_sorted) {
    int e = blockIdx.x * blockDim.x + threadIdx.x;
    if (e >= EP) return;
    int s, d; float w;
    if (e < EE) {
        s = ei[e]; d = ei[EE + e];
        float a = eattr[e];
        w = (a == 0.0f) ? 10000.0f : (1.0f / a);
    } else {
        s = d = e - EE;
        w = 0.0f;
    }
    int pos = row_ptr[d] + atomicAdd(&fill[d], 1);
    src_sorted[pos] = s;
    ew_sorted[pos] = w;
}

// ---------------------------------------------------------------- fused dual GEMM: xl = X@Wl, xr = X@Wr
// X tile staged row-major [32][128] (no transpose). Thread = (rowgroup t>>5)*4 rows
// x (colgroup t&31)*4 cols. x read along K via float4 (same addr across colgroups ->
// LDS broadcast, no conflicts). W float4 loads coalesced across colgroups.
#define GD_BM 32
__global__ __launch_bounds__(256, 2) void k_gemm_dual(const float* __restrict__ X,
        const float* __restrict__ Wl, const float* __restrict__ Wr,
        float* __restrict__ xl, float* __restrict__ xr, int nrows) {
    __shared__ f4 xs[GD_BM][32];    // [row][k/4]  16 KB
    int t = threadIdx.x;
    int rowbase = blockIdx.x * GD_BM;

    for (int i = t; i < GD_BM * 32; i += 256) {
        int r = i >> 5, kk = i & 31;
        int gr = rowbase + r;
        f4 v = {0.f, 0.f, 0.f, 0.f};
        if (gr < nrows) v = *(const f4*)&X[gr * DD + kk * 4];
        xs[r][kk] = v;
    }
    __syncthreads();

    int c0 = (t & 31) * 4;
    int r0 = (t >> 5) * 4;
    f4 accL[4], accR[4];
#pragma unroll
    for (int i = 0; i < 4; ++i) { accL[i] = (f4){0,0,0,0}; accR[i] = (f4){0,0,0,0}; }

    for (int kk = 0; kk < 32; ++kk) {
        f4 a0 = xs[r0 + 0][kk];
        f4 a1 = xs[r0 + 1][kk];
        f4 a2 = xs[r0 + 2][kk];
        f4 a3 = xs[r0 + 3][kk];
        const float* wlp = &Wl[(kk * 4) * DD + c0];
        const float* wrp = &Wr[(kk * 4) * DD + c0];
#define KSTEP(J, COMP) { \
        f4 wl = *(const f4*)&wlp[(J) * DD]; \
        f4 wr = *(const f4*)&wrp[(J) * DD]; \
        accL[0] += a0.COMP * wl; accL[1] += a1.COMP * wl; \
        accL[2] += a2.COMP * wl; accL[3] += a3.COMP * wl; \
        accR[0] += a0.COMP * wr; accR[1] += a1.COMP * wr; \
        accR[2] += a2.COMP * wr; accR[3] += a3.COMP * wr; }
        KSTEP(0, x) KSTEP(1, y) KSTEP(2, z) KSTEP(3, w)
#undef KSTEP
    }

#pragma unroll
    for (int i = 0; i < 4; ++i) {
        int row = rowbase + r0 + i;
        if (row < nrows) {
            *(f4*)&xl[row * DD + c0] = accL[i];
            *(f4*)&xr[row * DD + c0] = accR[i];
        }
    }
}

// ---------------------------------------------------------------- aggregation
// Wave per node; each 32-lane HALF processes its own edge stream (2 edges in
// flight), lane covers 4 channels (float4 -> 512B coalesced gather per edge
// per half). Independent online-softmax state per half, merged at the end.
__global__ __launch_bounds__(256) void k_agg(const float* __restrict__ xl,
        const float* __restrict__ xr, const int* __restrict__ row_ptr,
        const int* __restrict__ src_sorted, const float* __restrict__ ew_sorted,
        const float* __restrict__ We, const float* __restrict__ att,
        const float* __restrict__ bias, float* __restrict__ out, int do_relu) {
    int wid = (blockIdx.x * blockDim.x + threadIdx.x) >> 6;
    int lane = threadIdx.x & 63;
    if (wid >= NN) return;
    int half = lane >> 5;
    int c = (lane & 31) * 4;

    f4 xrv  = *(const f4*)&xr[wid * DD + c];
    f4 attv = *(const f4*)&att[c];
    f4 Wev  = *(const f4*)&We[c];
    f4 bv   = *(const f4*)&bias[c];

    int beg = row_ptr[wid];
    int end = row_ptr[wid + 1];
    int niter = (end - beg + 1) >> 1;

    float m = -1e30f;     // finite "minus infinity": keeps exp() NaN-free
    float d = 0.0f;
    f4 acc = {0.f, 0.f, 0.f, 0.f};

    for (int i = 0; i < niter; ++i) {
        int e = beg + 2 * i + half;
        bool valid = (e < end);
        int ee = valid ? e : (end - 1);
        int s = src_sorted[ee];
        float w = ew_sorted[ee];
        f4 xls = *(const f4*)&xl[s * DD + c];

        float t0 = xls.x + xrv.x + w * Wev.x; t0 = (t0 > 0.f) ? t0 : NEG_SLOPE * t0;
        float t1 = xls.y + xrv.y + w * Wev.y; t1 = (t1 > 0.f) ? t1 : NEG_SLOPE * t1;
        float t2 = xls.z + xrv.z + w * Wev.z; t2 = (t2 > 0.f) ? t2 : NEG_SLOPE * t2;
        float t3 = xls.w + xrv.w + w * Wev.w; t3 = (t3 > 0.f) ? t3 : NEG_SLOPE * t3;
        float p = t0 * attv.x + t1 * attv.y + t2 * attv.z + t3 * attv.w;
#pragma unroll
        for (int o = 16; o >= 1; o >>= 1) p += __shfl_xor(p, o, 64);   // within half

        float logit = valid ? p : -1e30f;
        float nm = fmaxf(m, logit);
        float sc = __expf(m - nm);
        float pe = __expf(logit - nm);
        d = d * sc + pe;
        acc = acc * sc + pe * xls;
        m = nm;
    }

    // merge the two half-wave states (lanes l and l+32 hold same channels)
    float mo = __shfl_xor(m, 32, 64);
    float dn = __shfl_xor(d, 32, 64);
    f4 ao;
    ao.x = __shfl_xor(acc.x, 32, 64);
    ao.y = __shfl_xor(acc.y, 32, 64);
    ao.z = __shfl_xor(acc.z, 32, 64);
    ao.w = __shfl_xor(acc.w, 32, 64);
    float M  = fmaxf(m, mo);
    float sA = __expf(m - M);
    float sB = __expf(mo - M);
    float dd = d * sA + dn * sB;
    f4 accF = acc * sA + ao * sB;

    f4 o = accF * (1.0f / dd) + bv;
    if (do_relu) {
        o.x = fmaxf(o.x, 0.f); o.y = fmaxf(o.y, 0.f);
        o.z = fmaxf(o.z, 0.f); o.w = fmaxf(o.w, 0.f);
    }
    if (half == 0) *(f4*)&out[wid * DD + c] = o;
}

// ---------------------------------------------------------------- final linear
__global__ __launch_bounds__(256) void k_final(const float* __restrict__ h,
        const float* __restrict__ Wlin, const float* __restrict__ blin,
        float* __restrict__ out) {
    int wid = (blockIdx.x * blockDim.x + threadIdx.x) >> 6;
    int lane = threadIdx.x & 63;
    if (wid >= NN) return;
    float2 hv = *(const float2*)&h[wid * DD + lane * 2];
    float2 wv = *(const float2*)&Wlin[lane * 2];
    float p = hv.x * wv.x + hv.y * wv.y;
#pragma unroll
    for (int o = 32; o >= 1; o >>= 1) p += __shfl_xor(p, o, 64);
    if (lane == 0) out[wid] = p + blin[0];
}

// ----------------------------------------------------------------
static inline size_t align256(size_t x) { return (x + 255) & ~(size_t)255; }

extern "C" void kernel_launch(void* const* d_in, const int* in_sizes, int n_in,
                              void* d_out, int out_size, void* d_ws, size_t ws_size,
                              hipStream_t stream) {
    const float* x     = (const float*)d_in[0];
    const int*   ei    = (const int*)d_in[1];
    const float* eattr = (const float*)d_in[2];
    const float* Wl[3]  = {(const float*)d_in[3],  (const float*)d_in[8],  (const float*)d_in[13]};
    const float* Wr[3]  = {(const float*)d_in[4],  (const float*)d_in[9],  (const float*)d_in[14]};
    const float* We[3]  = {(const float*)d_in[5],  (const float*)d_in[10], (const float*)d_in[15]};
    const float* att[3] = {(const float*)d_in[6],  (const float*)d_in[11], (const float*)d_in[16]};
    const float* bb[3]  = {(const float*)d_in[7],  (const float*)d_in[12], (const float*)d_in[17]};
    const float* Wlin = (const float*)d_in[18];
    const float* blin = (const float*)d_in[19];

    char* p = (char*)d_ws;
    int* counts = (int*)p;          p += align256((size_t)NN * 4);
    int* fill   = (int*)p;          p += align256((size_t)NN * 4);
    int* row_ptr= (int*)p;          p += align256((size_t)(NN + 1) * 4);
    int* blockSums = (int*)p;       p += align256(64 * 4);
    int* blockOffs = (int*)p;       p += align256(64 * 4);
    int* src_sorted = (int*)p;      p += align256((size_t)EP * 4);
    float* ew_sorted = (float*)p;   p += align256((size_t)EP * 4);
    float* xl = (float*)p;          p += align256((size_t)NN * DD * 4);
    float* xr = (float*)p;          p += align256((size_t)NN * DD * 4);
    float* hA = (float*)p;          p += align256((size_t)NN * DD * 4);
    float* hB = (float*)p;          p += align256((size_t)NN * DD * 4);

    hipMemsetAsync(counts, 0, align256((size_t)NN * 4) + align256((size_t)NN * 4), stream);

    const int nb_scan = (NN + 1023) / 1024;   // 49
    k_hist<<<(EP + 255) / 256, 256, 0, stream>>>(ei, counts);
    k_scan1<<<nb_scan, 1024, 0, stream>>>(counts, row_ptr, blockSums);
    k_scan2<<<1, 64, 0, stream>>>(blockSums, blockOffs, nb_scan, row_ptr);
    k_scan3<<<nb_scan, 1024, 0, stream>>>(row_ptr, blockOffs);
    k_scatter<<<(EP + 255) / 256, 256, 0, stream>>>(ei, eattr, row_ptr, fill, src_sorted, ew_sorted);

    const int gemm_grid = (NN + GD_BM - 1) / GD_BM;
    const int agg_grid  = (NN + 3) / 4;       // 4 waves per 256-thread block

    // layer 1: x -> hA (relu)
    k_gemm_dual<<<gemm_grid, 256, 0, stream>>>(x, Wl[0], Wr[0], xl, xr, NN);
    k_agg<<<agg_grid, 256, 0, stream>>>(xl, xr, row_ptr, src_sorted, ew_sorted,
                                        We[0], att[0], bb[0], hA, 1);
    // layer 2: hA -> hB (relu)
    k_gemm_dual<<<gemm_grid, 256, 0, stream>>>(hA, Wl[1], Wr[1], xl, xr, NN);
    k_agg<<<agg_grid, 256, 0, stream>>>(xl, xr, row_ptr, src_sorted, ew_sorted,
                                        We[1], att[1], bb[1], hB, 1);
    // layer 3: hB -> hA (no relu)
    k_gemm_dual<<<gemm_grid, 256, 0, stream>>>(hB, Wl[2], Wr[2], xl, xr, NN);
    k_agg<<<agg_grid, 256, 0, stream>>>(xl, xr, row_ptr, src_sorted, ew_sorted,
                                        We[2], att[2], bb[2], hA, 0);

    k_final<<<agg_grid, 256, 0, stream>>>(hA, Wlin, blin, (float*)d_out);
}

// Round 5
// 623.663 us; speedup vs baseline: 1.2908x; 1.0380x over previous
//
#include <hip/hip_runtime.h>
#include <math.h>

#define NN 50000
#define EE 800000
#define EP 850000   // EE + NN self loops
#define DD 128
#define NEG_SLOPE 0.2f

typedef float f4 __attribute__((ext_vector_type(4)));

// ---------------------------------------------------------------- histogram
__global__ void k_hist(const int* __restrict__ ei, int* __restrict__ counts) {
    int e = blockIdx.x * blockDim.x + threadIdx.x;
    if (e >= EP) return;
    int dst = (e < EE) ? ei[EE + e] : (e - EE);
    atomicAdd(&counts[dst], 1);
}

// ---------------------------------------------------------------- block scan
__global__ void k_scan1(const int* __restrict__ counts, int* __restrict__ row_ptr,
                        int* __restrict__ blockSums) {
    __shared__ int sm[1024];
    int t = threadIdx.x;
    int g = blockIdx.x * 1024 + t;
    int v = (g < NN) ? counts[g] : 0;
    sm[t] = v;
    __syncthreads();
    for (int off = 1; off < 1024; off <<= 1) {
        int add = (t >= off) ? sm[t - off] : 0;
        __syncthreads();
        sm[t] += add;
        __syncthreads();
    }
    if (g < NN) row_ptr[g] = sm[t] - v;   // exclusive
    if (t == 1023) blockSums[blockIdx.x] = sm[t];
}

__global__ void k_scan2(const int* __restrict__ blockSums, int* __restrict__ blockOffs,
                        int nb, int* __restrict__ row_ptr) {
    if (threadIdx.x == 0 && blockIdx.x == 0) {
        int run = 0;
        for (int i = 0; i < nb; ++i) { blockOffs[i] = run; run += blockSums[i]; }
        row_ptr[NN] = run;   // == EP
    }
}

__global__ void k_scan3(int* __restrict__ row_ptr, const int* __restrict__ blockOffs) {
    int g = blockIdx.x * 1024 + threadIdx.x;
    if (g < NN) row_ptr[g] += blockOffs[blockIdx.x];
}

// ---------------------------------------------------------------- scatter into CSR
__global__ void k_scatter(const int* __restrict__ ei, const float* __restrict__ eattr,
                          const int* __restrict__ row_ptr, int* __restrict__ fill,
                          int* __restrict__ src_sorted, float* __restrict__ ew_sorted) {
    int e = blockIdx.x * blockDim.x + threadIdx.x;
    if (e >= EP) return;
    int s, d; float w;
    if (e < EE) {
        s = ei[e]; d = ei[EE + e];
        float a = eattr[e];
        w = (a == 0.0f) ? 10000.0f : (1.0f / a);
    } else {
        s = d = e - EE;
        w = 0.0f;
    }
    int pos = row_ptr[d] + atomicAdd(&fill[d], 1);
    src_sorted[pos] = s;
    ew_sorted[pos] = w;
}

// ---------------------------------------------------------------- fused dual GEMM: xl = X@Wl, xr = X@Wr
// BM=64 rows/block, 256 threads, thread = 8 rows x 4 cols x 2 mats.
// X tile row-major in LDS (reads broadcast across col-groups). W streamed from
// global (L1/L2-resident) with explicit 2-deep register double-buffer so each
// 512-cycle FMA block hides the next chunk's load latency.
#define GD_BM 64
__global__ __launch_bounds__(256, 2) void k_gemm_dual(const float* __restrict__ X,
        const float* __restrict__ Wl, const float* __restrict__ Wr,
        float* __restrict__ xl, float* __restrict__ xr, int nrows) {
    __shared__ f4 xs[GD_BM][32];    // [row][k/4]  32 KB
    int t = threadIdx.x;
    int rowbase = blockIdx.x * GD_BM;

#pragma unroll
    for (int i = 0; i < 8; ++i) {
        int idx = t + i * 256;
        int r = idx >> 5, kk = idx & 31;
        int gr = rowbase + r;
        f4 v = {0.f, 0.f, 0.f, 0.f};
        if (gr < nrows) v = *(const f4*)&X[gr * DD + kk * 4];
        xs[r][kk] = v;
    }
    __syncthreads();

    int c0 = (t & 31) * 4;
    int r0 = (t >> 5) * 8;
    f4 accL[8], accR[8];
#pragma unroll
    for (int i = 0; i < 8; ++i) { accL[i] = (f4){0,0,0,0}; accR[i] = (f4){0,0,0,0}; }

    const float* wlp = Wl + c0;
    const float* wrp = Wr + c0;

    f4 wlA[4], wrA[4], wlB[4], wrB[4];
    f4 aA[8], aB[8];

    // prologue: chunk 0 into A buffers
#pragma unroll
    for (int j = 0; j < 4; ++j) {
        wlA[j] = *(const f4*)&wlp[j * DD];
        wrA[j] = *(const f4*)&wrp[j * DD];
    }
#pragma unroll
    for (int i = 0; i < 8; ++i) aA[i] = xs[r0 + i][0];

#define FMA_STEP(WLBUF, WRBUF, ABUF) \
    { _Pragma("unroll") \
      for (int j = 0; j < 4; ++j) { \
        _Pragma("unroll") \
        for (int i = 0; i < 8; ++i) { \
            float av = ABUF[i][j]; \
            accL[i] += av * WLBUF[j]; \
            accR[i] += av * WRBUF[j]; \
        } } }

    for (int kk = 0; kk < 32; kk += 2) {
        // prefetch chunk kk+1 into B (kk max 30 -> kk+1 always valid)
#pragma unroll
        for (int j = 0; j < 4; ++j) {
            wlB[j] = *(const f4*)&wlp[((kk + 1) * 4 + j) * DD];
            wrB[j] = *(const f4*)&wrp[((kk + 1) * 4 + j) * DD];
        }
#pragma unroll
        for (int i = 0; i < 8; ++i) aB[i] = xs[r0 + i][kk + 1];

        FMA_STEP(wlA, wrA, aA)

        if (kk < 30) {   // prefetch chunk kk+2 into A
#pragma unroll
            for (int j = 0; j < 4; ++j) {
                wlA[j] = *(const f4*)&wlp[((kk + 2) * 4 + j) * DD];
                wrA[j] = *(const f4*)&wrp[((kk + 2) * 4 + j) * DD];
            }
#pragma unroll
            for (int i = 0; i < 8; ++i) aA[i] = xs[r0 + i][kk + 2];
        }

        FMA_STEP(wlB, wrB, aB)
    }
#undef FMA_STEP

#pragma unroll
    for (int i = 0; i < 8; ++i) {
        int row = rowbase + r0 + i;
        if (row < nrows) {
            *(f4*)&xl[row * DD + c0] = accL[i];
            *(f4*)&xr[row * DD + c0] = accR[i];
        }
    }
}

// ---------------------------------------------------------------- aggregation
// Wave per node; each 16-lane QUARTER processes its own edge stream (4 edges
// in flight), lane covers 8 channels (2x float4). Independent online-softmax
// state per quarter, merged pairwise at the end.
__device__ inline f4 lrelu4(f4 v) {
    f4 r;
    r.x = v.x > 0.f ? v.x : NEG_SLOPE * v.x;
    r.y = v.y > 0.f ? v.y : NEG_SLOPE * v.y;
    r.z = v.z > 0.f ? v.z : NEG_SLOPE * v.z;
    r.w = v.w > 0.f ? v.w : NEG_SLOPE * v.w;
    return r;
}

__global__ __launch_bounds__(256) void k_agg(const float* __restrict__ xl,
        const float* __restrict__ xr, const int* __restrict__ row_ptr,
        const int* __restrict__ src_sorted, const float* __restrict__ ew_sorted,
        const float* __restrict__ We, const float* __restrict__ att,
        const float* __restrict__ bias, float* __restrict__ out, int do_relu) {
    int wid = (blockIdx.x * blockDim.x + threadIdx.x) >> 6;
    int lane = threadIdx.x & 63;
    if (wid >= NN) return;
    int quarter = lane >> 4;       // 0..3
    int c = (lane & 15) * 8;       // 8 channels per lane

    const f4 xrv0 = *(const f4*)&xr[wid * DD + c];
    const f4 xrv1 = *(const f4*)&xr[wid * DD + c + 4];
    const f4 att0 = *(const f4*)&att[c];
    const f4 att1 = *(const f4*)&att[c + 4];
    const f4 We0  = *(const f4*)&We[c];
    const f4 We1  = *(const f4*)&We[c + 4];

    int beg = row_ptr[wid];
    int end = row_ptr[wid + 1];
    int niter = (end - beg + 3) >> 2;

    float m = -1e30f;     // finite "minus infinity": keeps exp() NaN-free
    float d = 0.0f;
    f4 acc0 = {0,0,0,0}, acc1 = {0,0,0,0};

    for (int i = 0; i < niter; ++i) {
        int e = beg + 4 * i + quarter;
        bool valid = (e < end);
        int ee = valid ? e : (end - 1);
        int s = src_sorted[ee];
        float w = ew_sorted[ee];
        f4 x0 = *(const f4*)&xl[s * DD + c];
        f4 x1 = *(const f4*)&xl[s * DD + c + 4];

        f4 t0 = lrelu4(x0 + xrv0 + w * We0);
        f4 t1 = lrelu4(x1 + xrv1 + w * We1);
        float p = t0.x * att0.x + t0.y * att0.y + t0.z * att0.z + t0.w * att0.w
                + t1.x * att1.x + t1.y * att1.y + t1.z * att1.z + t1.w * att1.w;
#pragma unroll
        for (int o = 8; o >= 1; o >>= 1) p += __shfl_xor(p, o, 64);   // within quarter

        float logit = valid ? p : -1e30f;
        float nm = fmaxf(m, logit);
        float sc = __expf(m - nm);
        float pe = __expf(logit - nm);
        d = d * sc + pe;
        acc0 = acc0 * sc + pe * x0;
        acc1 = acc1 * sc + pe * x1;
        m = nm;
    }

    // merge the 4 quarter states (lanes l, l+16, l+32, l+48 hold same channels)
#pragma unroll
    for (int o = 16; o <= 32; o <<= 1) {
        float mo = __shfl_xor(m, o, 64);
        float dn = __shfl_xor(d, o, 64);
        f4 a0o, a1o;
        a0o.x = __shfl_xor(acc0.x, o, 64); a0o.y = __shfl_xor(acc0.y, o, 64);
        a0o.z = __shfl_xor(acc0.z, o, 64); a0o.w = __shfl_xor(acc0.w, o, 64);
        a1o.x = __shfl_xor(acc1.x, o, 64); a1o.y = __shfl_xor(acc1.y, o, 64);
        a1o.z = __shfl_xor(acc1.z, o, 64); a1o.w = __shfl_xor(acc1.w, o, 64);
        float M  = fmaxf(m, mo);
        float sA = __expf(m - M);
        float sB = __expf(mo - M);
        d = d * sA + dn * sB;
        acc0 = acc0 * sA + a0o * sB;
        acc1 = acc1 * sA + a1o * sB;
        m = M;
    }

    if (quarter == 0) {
        float inv = 1.0f / d;
        f4 bv0 = *(const f4*)&bias[c];
        f4 bv1 = *(const f4*)&bias[c + 4];
        f4 o0 = acc0 * inv + bv0;
        f4 o1 = acc1 * inv + bv1;
        if (do_relu) {
            o0.x = fmaxf(o0.x, 0.f); o0.y = fmaxf(o0.y, 0.f);
            o0.z = fmaxf(o0.z, 0.f); o0.w = fmaxf(o0.w, 0.f);
            o1.x = fmaxf(o1.x, 0.f); o1.y = fmaxf(o1.y, 0.f);
            o1.z = fmaxf(o1.z, 0.f); o1.w = fmaxf(o1.w, 0.f);
        }
        *(f4*)&out[wid * DD + c] = o0;
        *(f4*)&out[wid * DD + c + 4] = o1;
    }
}

// ---------------------------------------------------------------- final linear
__global__ __launch_bounds__(256) void k_final(const float* __restrict__ h,
        const float* __restrict__ Wlin, const float* __restrict__ blin,
        float* __restrict__ out) {
    int wid = (blockIdx.x * blockDim.x + threadIdx.x) >> 6;
    int lane = threadIdx.x & 63;
    if (wid >= NN) return;
    float2 hv = *(const float2*)&h[wid * DD + lane * 2];
    float2 wv = *(const float2*)&Wlin[lane * 2];
    float p = hv.x * wv.x + hv.y * wv.y;
#pragma unroll
    for (int o = 32; o >= 1; o >>= 1) p += __shfl_xor(p, o, 64);
    if (lane == 0) out[wid] = p + blin[0];
}

// ----------------------------------------------------------------
static inline size_t align256(size_t x) { return (x + 255) & ~(size_t)255; }

extern "C" void kernel_launch(void* const* d_in, const int* in_sizes, int n_in,
                              void* d_out, int out_size, void* d_ws, size_t ws_size,
                              hipStream_t stream) {
    const float* x     = (const float*)d_in[0];
    const int*   ei    = (const int*)d_in[1];
    const float* eattr = (const float*)d_in[2];
    const float* Wl[3]  = {(const float*)d_in[3],  (const float*)d_in[8],  (const float*)d_in[13]};
    const float* Wr[3]  = {(const float*)d_in[4],  (const float*)d_in[9],  (const float*)d_in[14]};
    const float* We[3]  = {(const float*)d_in[5],  (const float*)d_in[10], (const float*)d_in[15]};
    const float* att[3] = {(const float*)d_in[6],  (const float*)d_in[11], (const float*)d_in[16]};
    const float* bb[3]  = {(const float*)d_in[7],  (const float*)d_in[12], (const float*)d_in[17]};
    const float* Wlin = (const float*)d_in[18];
    const float* blin = (const float*)d_in[19];

    char* p = (char*)d_ws;
    int* counts = (int*)p;          p += align256((size_t)NN * 4);
    int* fill   = (int*)p;          p += align256((size_t)NN * 4);
    int* row_ptr= (int*)p;          p += align256((size_t)(NN + 1) * 4);
    int* blockSums = (int*)p;       p += align256(64 * 4);
    int* blockOffs = (int*)p;       p += align256(64 * 4);
    int* src_sorted = (int*)p;      p += align256((size_t)EP * 4);
    float* ew_sorted = (float*)p;   p += align256((size_t)EP * 4);
    float* xl = (float*)p;          p += align256((size_t)NN * DD * 4);
    float* xr = (float*)p;          p += align256((size_t)NN * DD * 4);
    float* hA = (float*)p;          p += align256((size_t)NN * DD * 4);
    float* hB = (float*)p;          p += align256((size_t)NN * DD * 4);

    hipMemsetAsync(counts, 0, align256((size_t)NN * 4) + align256((size_t)NN * 4), stream);

    const int nb_scan = (NN + 1023) / 1024;   // 49
    k_hist<<<(EP + 255) / 256, 256, 0, stream>>>(ei, counts);
    k_scan1<<<nb_scan, 1024, 0, stream>>>(counts, row_ptr, blockSums);
    k_scan2<<<1, 64, 0, stream>>>(blockSums, blockOffs, nb_scan, row_ptr);
    k_scan3<<<nb_scan, 1024, 0, stream>>>(row_ptr, blockOffs);
    k_scatter<<<(EP + 255) / 256, 256, 0, stream>>>(ei, eattr, row_ptr, fill, src_sorted, ew_sorted);

    const int gemm_grid = (NN + GD_BM - 1) / GD_BM;
    const int agg_grid  = (NN + 3) / 4;       // 4 waves per 256-thread block

    // layer 1: x -> hA (relu)
    k_gemm_dual<<<gemm_grid, 256, 0, stream>>>(x, Wl[0], Wr[0], xl, xr, NN);
    k_agg<<<agg_grid, 256, 0, stream>>>(xl, xr, row_ptr, src_sorted, ew_sorted,
                                        We[0], att[0], bb[0], hA, 1);
    // layer 2: hA -> hB (relu)
    k_gemm_dual<<<gemm_grid, 256, 0, stream>>>(hA, Wl[1], Wr[1], xl, xr, NN);
    k_agg<<<agg_grid, 256, 0, stream>>>(xl, xr, row_ptr, src_sorted, ew_sorted,
                                        We[1], att[1], bb[1], hB, 1);
    // layer 3: hB -> hA (no relu)
    k_gemm_dual<<<gemm_grid, 256, 0, stream>>>(hB, Wl[2], Wr[2], xl, xr, NN);
    k_agg<<<agg_grid, 256, 0, stream>>>(xl, xr, row_ptr, src_sorted, ew_sorted,
                                        We[2], att[2], bb[2], hA, 0);

    k_final<<<agg_grid, 256, 0, stream>>>(hA, Wlin, blin, (float*)d_out);
}

// Round 8
// 555.681 us; speedup vs baseline: 1.4488x; 1.1223x over previous
//
#include <hip/hip_runtime.h>
#include <math.h>

#define NN 50000
#define EE 800000
#define EP 850000   // EE + NN self loops
#define DD 128
#define NEG_SLOPE 0.2f

typedef float f4 __attribute__((ext_vector_type(4)));

// ---------------------------------------------------------------- histogram
__global__ void k_hist(const int* __restrict__ ei, int* __restrict__ counts) {
    int e = blockIdx.x * blockDim.x + threadIdx.x;
    if (e >= EP) return;
    int dst = (e < EE) ? ei[EE + e] : (e - EE);
    atomicAdd(&counts[dst], 1);
}

// ---------------------------------------------------------------- block scan (wave-shfl based)
__global__ void k_scan1(const int* __restrict__ counts, int* __restrict__ row_ptr,
                        int* __restrict__ blockSums) {
    __shared__ int wsum[16];
    int t = threadIdx.x;
    int lane = t & 63;
    int wave = t >> 6;            // 0..15
    int g = blockIdx.x * 1024 + t;
    int v = (g < NN) ? counts[g] : 0;

    int s = v;                    // inclusive scan within wave
#pragma unroll
    for (int o = 1; o < 64; o <<= 1) {
        int u = __shfl_up(s, o, 64);
        if (lane >= o) s += u;
    }
    if (lane == 63) wsum[wave] = s;
    __syncthreads();
    if (wave == 0) {
        int ws = (lane < 16) ? wsum[lane] : 0;
#pragma unroll
        for (int o = 1; o < 16; o <<= 1) {
            int u = __shfl_up(ws, o, 64);
            if (lane >= o) ws += u;
        }
        if (lane < 16) wsum[lane] = ws;
    }
    __syncthreads();
    int base = (wave > 0) ? wsum[wave - 1] : 0;
    int incl = base + s;
    if (g < NN) row_ptr[g] = incl - v;   // exclusive
    if (t == 1023) blockSums[blockIdx.x] = incl;
}

__global__ void k_scan2(const int* __restrict__ blockSums, int* __restrict__ blockOffs,
                        int nb, int* __restrict__ row_ptr) {
    if (threadIdx.x == 0 && blockIdx.x == 0) {
        int run = 0;
        for (int i = 0; i < nb; ++i) { blockOffs[i] = run; run += blockSums[i]; }
        row_ptr[NN] = run;   // == EP
    }
}

__global__ void k_scan3(int* __restrict__ row_ptr, const int* __restrict__ blockOffs) {
    int g = blockIdx.x * 1024 + threadIdx.x;
    if (g < NN) row_ptr[g] += blockOffs[blockIdx.x];
}

// ---------------------------------------------------------------- scatter into CSR
__global__ void k_scatter(const int* __restrict__ ei, const float* __restrict__ eattr,
                          const int* __restrict__ row_ptr, int* __restrict__ fill,
                          int* __restrict__ src_sorted, float* __restrict__ ew_sorted) {
    int e = blockIdx.x * blockDim.x + threadIdx.x;
    if (e >= EP) return;
    int s, d; float w;
    if (e < EE) {
        s = ei[e]; d = ei[EE + e];
        float a = eattr[e];
        w = (a == 0.0f) ? 10000.0f : (1.0f / a);
    } else {
        s = d = e - EE;
        w = 0.0f;
    }
    int pos = row_ptr[d] + atomicAdd(&fill[d], 1);
    src_sorted[pos] = s;
    ew_sorted[pos] = w;
}

// ---------------------------------------------------------------- fused dual GEMM: xl = X@Wl, xr = X@Wr
// Block = 64 rows x 128 cols, 256 threads (8 rowgroups x 32 colgroups),
// thread = 8 rows x 4 cols x 2 mats. X tile (32KB) staged once in LDS; W
// streamed through an LDS double-buffer in 8-k-row chunks (4KB/mat/chunk):
// prefetch next chunk to regs -> compute current from LDS -> ds_write -> one
// barrier. LDS latency needs no deep register pipeline, so the register
// allocator can't defeat the overlap (round-5 lesson: VGPR cap killed the
// register double-buffer).
#define GD_BM 64
#define KC 8
__global__ __launch_bounds__(256, 2) void k_gemm_dual(const float* __restrict__ X,
        const float* __restrict__ Wl, const float* __restrict__ Wr,
        float* __restrict__ xl, float* __restrict__ xr, int nrows) {
    __shared__ f4 xs[GD_BM][32];        // 32 KB
    __shared__ f4 wls[2][KC][32];       // 8 KB
    __shared__ f4 wrs[2][KC][32];       // 8 KB
    int t = threadIdx.x;
    int rowbase = blockIdx.x * GD_BM;

    // stage X tile
#pragma unroll
    for (int i = 0; i < 8; ++i) {
        int idx = t + i * 256;
        int r = idx >> 5, kk = idx & 31;
        int gr = rowbase + r;
        f4 v = {0.f, 0.f, 0.f, 0.f};
        if (gr < nrows) v = *(const f4*)&X[gr * DD + kk * 4];
        xs[r][kk] = v;
    }
    // stage W chunk 0
    int wk = t >> 5, wc = t & 31;
    wls[0][wk][wc] = *(const f4*)&Wl[wk * DD + wc * 4];
    wrs[0][wk][wc] = *(const f4*)&Wr[wk * DD + wc * 4];
    __syncthreads();

    int c0 = t & 31;           // colgroup (f4 index)
    int r0 = (t >> 5) * 8;     // first of 8 rows
    f4 accL[8], accR[8];
#pragma unroll
    for (int i = 0; i < 8; ++i) { accL[i] = (f4){0,0,0,0}; accR[i] = (f4){0,0,0,0}; }

    int buf = 0;
    for (int ch = 0; ch < 16; ++ch) {
        // prefetch next W chunk into registers (covered by the FMA block below)
        f4 pl, pr;
        if (ch < 15) {
            int kg = (ch + 1) * KC + wk;
            pl = *(const f4*)&Wl[kg * DD + wc * 4];
            pr = *(const f4*)&Wr[kg * DD + wc * 4];
        }
        // compute chunk ch from LDS
#pragma unroll
        for (int k4 = 0; k4 < KC / 4; ++k4) {
            f4 a[8];
#pragma unroll
            for (int i = 0; i < 8; ++i) a[i] = xs[r0 + i][ch * 2 + k4];
#pragma unroll
            for (int j = 0; j < 4; ++j) {
                f4 wl = wls[buf][k4 * 4 + j][c0];
                f4 wr = wrs[buf][k4 * 4 + j][c0];
#pragma unroll
                for (int i = 0; i < 8; ++i) {
                    float av = a[i][j];
                    accL[i] += av * wl;
                    accR[i] += av * wr;
                }
            }
        }
        // publish prefetched chunk; one barrier per chunk
        if (ch < 15) {
            wls[buf ^ 1][wk][wc] = pl;
            wrs[buf ^ 1][wk][wc] = pr;
            __syncthreads();
        }
        buf ^= 1;
    }

#pragma unroll
    for (int i = 0; i < 8; ++i) {
        int row = rowbase + r0 + i;
        if (row < nrows) {
            *(f4*)&xl[row * DD + c0 * 4] = accL[i];
            *(f4*)&xr[row * DD + c0 * 4] = accR[i];
        }
    }
}

// ---------------------------------------------------------------- aggregation
// Wave per node; each 16-lane QUARTER owns its own edge stream (4 edges in
// flight per wave), lane covers 8 channels. Online softmax per quarter,
// merged pairwise at the end. Next iteration's (index, weight, gather) is
// prefetched before the current compute to hide the dependent load chain.
// FUSE_FINAL: layer 3 skips writing h and directly dots with Wlin.
__device__ inline f4 lrelu4(f4 v) {
    f4 r;
    r.x = v.x > 0.f ? v.x : NEG_SLOPE * v.x;
    r.y = v.y > 0.f ? v.y : NEG_SLOPE * v.y;
    r.z = v.z > 0.f ? v.z : NEG_SLOPE * v.z;
    r.w = v.w > 0.f ? v.w : NEG_SLOPE * v.w;
    return r;
}

template<bool DO_RELU, bool FUSE_FINAL>
__global__ __launch_bounds__(256) void k_agg_t(const float* __restrict__ xl,
        const float* __restrict__ xr, const int* __restrict__ row_ptr,
        const int* __restrict__ src_sorted, const float* __restrict__ ew_sorted,
        const float* __restrict__ We, const float* __restrict__ att,
        const float* __restrict__ bias, float* __restrict__ out,
        const float* __restrict__ Wlin, const float* __restrict__ blin,
        float* __restrict__ outS) {
    int wid = (blockIdx.x * blockDim.x + threadIdx.x) >> 6;
    int lane = threadIdx.x & 63;
    if (wid >= NN) return;
    int quarter = lane >> 4;       // 0..3
    int c = (lane & 15) * 8;       // 8 channels per lane

    const f4 xrv0 = *(const f4*)&xr[wid * DD + c];
    const f4 xrv1 = *(const f4*)&xr[wid * DD + c + 4];
    const f4 att0 = *(const f4*)&att[c];
    const f4 att1 = *(const f4*)&att[c + 4];
    const f4 We0  = *(const f4*)&We[c];
    const f4 We1  = *(const f4*)&We[c + 4];

    int beg = row_ptr[wid];
    int end = row_ptr[wid + 1];
    int niter = (end - beg + 3) >> 2;

    float m = -1e30f;     // finite "minus infinity": keeps exp() NaN-free
    float d = 0.0f;
    f4 acc0 = {0,0,0,0}, acc1 = {0,0,0,0};

    // prologue: load iteration 0's edge data
    int e0 = beg + quarter;
    bool val_cur = (e0 < end);
    int ee0 = val_cur ? e0 : (end - 1);
    float w_cur = ew_sorted[ee0];
    int s_cur = src_sorted[ee0];
    f4 x0c = *(const f4*)&xl[s_cur * DD + c];
    f4 x1c = *(const f4*)&xl[s_cur * DD + c + 4];

    for (int i = 0; i < niter; ++i) {
        // prefetch iteration i+1 (independent of the softmax chain)
        f4 x0n = {0,0,0,0}, x1n = {0,0,0,0};
        float w_nxt = 0.f; bool val_nxt = false;
        if (i + 1 < niter) {
            int e = beg + 4 * (i + 1) + quarter;
            val_nxt = (e < end);
            int ee = val_nxt ? e : (end - 1);
            w_nxt = ew_sorted[ee];
            int sn = src_sorted[ee];
            x0n = *(const f4*)&xl[sn * DD + c];
            x1n = *(const f4*)&xl[sn * DD + c + 4];
        }

        f4 t0 = lrelu4(x0c + xrv0 + w_cur * We0);
        f4 t1 = lrelu4(x1c + xrv1 + w_cur * We1);
        float p = t0.x * att0.x + t0.y * att0.y + t0.z * att0.z + t0.w * att0.w
                + t1.x * att1.x + t1.y * att1.y + t1.z * att1.z + t1.w * att1.w;
#pragma unroll
        for (int o = 8; o >= 1; o >>= 1) p += __shfl_xor(p, o, 64);   // within quarter

        float logit = val_cur ? p : -1e30f;
        float nm = fmaxf(m, logit);
        float sc = __expf(m - nm);
        float pe = __expf(logit - nm);
        d = d * sc + pe;
        acc0 = acc0 * sc + pe * x0c;
        acc1 = acc1 * sc + pe * x1c;
        m = nm;

        x0c = x0n; x1c = x1n; w_cur = w_nxt; val_cur = val_nxt;
    }

    // merge the 4 quarter states (lanes l, l+16, l+32, l+48 hold same channels)
#pragma unroll
    for (int o = 16; o <= 32; o <<= 1) {
        float mo = __shfl_xor(m, o, 64);
        float dn = __shfl_xor(d, o, 64);
        f4 a0o, a1o;
        a0o.x = __shfl_xor(acc0.x, o, 64); a0o.y = __shfl_xor(acc0.y, o, 64);
        a0o.z = __shfl_xor(acc0.z, o, 64); a0o.w = __shfl_xor(acc0.w, o, 64);
        a1o.x = __shfl_xor(acc1.x, o, 64); a1o.y = __shfl_xor(acc1.y, o, 64);
        a1o.z = __shfl_xor(acc1.z, o, 64); a1o.w = __shfl_xor(acc1.w, o, 64);
        float M  = fmaxf(m, mo);
        float sA = __expf(m - M);
        float sB = __expf(mo - M);
        d = d * sA + dn * sB;
        acc0 = acc0 * sA + a0o * sB;
        acc1 = acc1 * sA + a1o * sB;
        m = M;
    }

    if (quarter == 0) {
        float inv = 1.0f / d;
        f4 bv0 = *(const f4*)&bias[c];
        f4 bv1 = *(const f4*)&bias[c + 4];
        f4 o0 = acc0 * inv + bv0;
        f4 o1 = acc1 * inv + bv1;
        if (DO_RELU) {
            o0.x = fmaxf(o0.x, 0.f); o0.y = fmaxf(o0.y, 0.f);
            o0.z = fmaxf(o0.z, 0.f); o0.w = fmaxf(o0.w, 0.f);
            o1.x = fmaxf(o1.x, 0.f); o1.y = fmaxf(o1.y, 0.f);
            o1.z = fmaxf(o1.z, 0.f); o1.w = fmaxf(o1.w, 0.f);
        }
        if (FUSE_FINAL) {
            // out[wid] = h[wid] . Wlin + blin, h never materialized
            f4 wl0 = *(const f4*)&Wlin[c];
            f4 wl1 = *(const f4*)&Wlin[c + 4];
            float p = o0.x * wl0.x + o0.y * wl0.y + o0.z * wl0.z + o0.w * wl0.w
                    + o1.x * wl1.x + o1.y * wl1.y + o1.z * wl1.z + o1.w * wl1.w;
#pragma unroll
            for (int o = 8; o >= 1; o >>= 1) p += __shfl_xor(p, o, 64);
            if (lane == 0) outS[wid] = p + blin[0];
        } else {
            *(f4*)&out[wid * DD + c] = o0;
            *(f4*)&out[wid * DD + c + 4] = o1;
        }
    }
}

// ----------------------------------------------------------------
static inline size_t align256(size_t x) { return (x + 255) & ~(size_t)255; }

extern "C" void kernel_launch(void* const* d_in, const int* in_sizes, int n_in,
                              void* d_out, int out_size, void* d_ws, size_t ws_size,
                              hipStream_t stream) {
    const float* x     = (const float*)d_in[0];
    const int*   ei    = (const int*)d_in[1];
    const float* eattr = (const float*)d_in[2];
    const float* Wl[3]  = {(const float*)d_in[3],  (const float*)d_in[8],  (const float*)d_in[13]};
    const float* Wr[3]  = {(const float*)d_in[4],  (const float*)d_in[9],  (const float*)d_in[14]};
    const float* We[3]  = {(const float*)d_in[5],  (const float*)d_in[10], (const float*)d_in[15]};
    const float* att[3] = {(const float*)d_in[6],  (const float*)d_in[11], (const float*)d_in[16]};
    const float* bb[3]  = {(const float*)d_in[7],  (const float*)d_in[12], (const float*)d_in[17]};
    const float* Wlin = (const float*)d_in[18];
    const float* blin = (const float*)d_in[19];

    char* p = (char*)d_ws;
    int* counts = (int*)p;          p += align256((size_t)NN * 4);
    int* fill   = (int*)p;          p += align256((size_t)NN * 4);
    int* row_ptr= (int*)p;          p += align256((size_t)(NN + 1) * 4);
    int* blockSums = (int*)p;       p += align256(64 * 4);
    int* blockOffs = (int*)p;       p += align256(64 * 4);
    int* src_sorted = (int*)p;      p += align256((size_t)EP * 4);
    float* ew_sorted = (float*)p;   p += align256((size_t)EP * 4);
    float* xl = (float*)p;          p += align256((size_t)NN * DD * 4);
    float* xr = (float*)p;          p += align256((size_t)NN * DD * 4);
    float* hA = (float*)p;          p += align256((size_t)NN * DD * 4);
    float* hB = (float*)p;          p += align256((size_t)NN * DD * 4);

    hipMemsetAsync(counts, 0, align256((size_t)NN * 4) + align256((size_t)NN * 4), stream);

    const int nb_scan = (NN + 1023) / 1024;   // 49
    k_hist<<<(EP + 255) / 256, 256, 0, stream>>>(ei, counts);
    k_scan1<<<nb_scan, 1024, 0, stream>>>(counts, row_ptr, blockSums);
    k_scan2<<<1, 64, 0, stream>>>(blockSums, blockOffs, nb_scan, row_ptr);
    k_scan3<<<nb_scan, 1024, 0, stream>>>(row_ptr, blockOffs);
    k_scatter<<<(EP + 255) / 256, 256, 0, stream>>>(ei, eattr, row_ptr, fill, src_sorted, ew_sorted);

    const int gemm_grid = (NN + GD_BM - 1) / GD_BM;
    const int agg_grid  = (NN + 3) / 4;       // 4 waves per 256-thread block

    // layer 1: x -> hA (relu)
    k_gemm_dual<<<gemm_grid, 256, 0, stream>>>(x, Wl[0], Wr[0], xl, xr, NN);
    k_agg_t<true, false><<<agg_grid, 256, 0, stream>>>(xl, xr, row_ptr, src_sorted, ew_sorted,
                                        We[0], att[0], bb[0], hA, nullptr, nullptr, nullptr);
    // layer 2: hA -> hB (relu)
    k_gemm_dual<<<gemm_grid, 256, 0, stream>>>(hA, Wl[1], Wr[1], xl, xr, NN);
    k_agg_t<true, false><<<agg_grid, 256, 0, stream>>>(xl, xr, row_ptr, src_sorted, ew_sorted,
                                        We[1], att[1], bb[1], hB, nullptr, nullptr, nullptr);
    // layer 3: hB -> (fused final linear) -> d_out
    k_gemm_dual<<<gemm_grid, 256, 0, stream>>>(hB, Wl[2], Wr[2], xl, xr, NN);
    k_agg_t<false, true><<<agg_grid, 256, 0, stream>>>(xl, xr, row_ptr, src_sorted, ew_sorted,
                                        We[2], att[2], bb[2], nullptr, Wlin, blin, (float*)d_out);
}

// Round 9
// 479.611 us; speedup vs baseline: 1.6786x; 1.1586x over previous
//
#include <hip/hip_runtime.h>
#include <math.h>

#define NN 50000
#define EE 800000
#define EP 850000   // EE + NN self loops
#define DD 128
#define NEG_SLOPE 0.2f

typedef float f4  __attribute__((ext_vector_type(4)));
typedef float f32x4 __attribute__((ext_vector_type(4)));
typedef short bf16x8 __attribute__((ext_vector_type(8)));
typedef short s4 __attribute__((ext_vector_type(4)));

// bf16 round-to-nearest-even, header-version-proof
static __device__ inline short f2bf(float f) {
    unsigned u = __float_as_uint(f);
    unsigned r = (u + 0x7FFFu + ((u >> 16) & 1u)) >> 16;
    return (short)r;
}
static __device__ inline float bf2f(short s) {
    return __uint_as_float(((unsigned)(unsigned short)s) << 16);
}

// ---------------------------------------------------------------- histogram
__global__ void k_hist(const int* __restrict__ ei, int* __restrict__ counts) {
    int e = blockIdx.x * blockDim.x + threadIdx.x;
    if (e >= EP) return;
    int dst = (e < EE) ? ei[EE + e] : (e - EE);
    atomicAdd(&counts[dst], 1);
}

// ---------------------------------------------------------------- block scan (wave-shfl based)
__global__ void k_scan1(const int* __restrict__ counts, int* __restrict__ row_ptr,
                        int* __restrict__ blockSums) {
    __shared__ int wsum[16];
    int t = threadIdx.x;
    int lane = t & 63;
    int wave = t >> 6;            // 0..15
    int g = blockIdx.x * 1024 + t;
    int v = (g < NN) ? counts[g] : 0;

    int s = v;                    // inclusive scan within wave
#pragma unroll
    for (int o = 1; o < 64; o <<= 1) {
        int u = __shfl_up(s, o, 64);
        if (lane >= o) s += u;
    }
    if (lane == 63) wsum[wave] = s;
    __syncthreads();
    if (wave == 0) {
        int ws = (lane < 16) ? wsum[lane] : 0;
#pragma unroll
        for (int o = 1; o < 16; o <<= 1) {
            int u = __shfl_up(ws, o, 64);
            if (lane >= o) ws += u;
        }
        if (lane < 16) wsum[lane] = ws;
    }
    __syncthreads();
    int base = (wave > 0) ? wsum[wave - 1] : 0;
    int incl = base + s;
    if (g < NN) row_ptr[g] = incl - v;   // exclusive
    if (t == 1023) blockSums[blockIdx.x] = incl;
}

__global__ void k_scan2(const int* __restrict__ blockSums, int* __restrict__ blockOffs,
                        int nb, int* __restrict__ row_ptr) {
    if (threadIdx.x == 0 && blockIdx.x == 0) {
        int run = 0;
        for (int i = 0; i < nb; ++i) { blockOffs[i] = run; run += blockSums[i]; }
        row_ptr[NN] = run;   // == EP
    }
}

__global__ void k_scan3(int* __restrict__ row_ptr, const int* __restrict__ blockOffs) {
    int g = blockIdx.x * 1024 + threadIdx.x;
    if (g < NN) row_ptr[g] += blockOffs[blockIdx.x];
}

// ---------------------------------------------------------------- scatter into CSR
__global__ void k_scatter(const int* __restrict__ ei, const float* __restrict__ eattr,
                          const int* __restrict__ row_ptr, int* __restrict__ fill,
                          int* __restrict__ src_sorted, float* __restrict__ ew_sorted) {
    int e = blockIdx.x * blockDim.x + threadIdx.x;
    if (e >= EP) return;
    int s, d; float w;
    if (e < EE) {
        s = ei[e]; d = ei[EE + e];
        float a = eattr[e];
        w = (a == 0.0f) ? 10000.0f : (1.0f / a);
    } else {
        s = d = e - EE;
        w = 0.0f;
    }
    int pos = row_ptr[d] + atomicAdd(&fill[d], 1);
    src_sorted[pos] = s;
    ew_sorted[pos] = w;
}

// ---------------------------------------------------------------- W pre-pack (hi/lo bf16, MFMA B-fragment order)
// B-frag layout for mfma_f32_16x16x32_bf16: lane l holds col = l&15,
// k = (l>>4)*8 + j (j=0..7, contiguous 16B per lane).
// dst layout (shorts): [layer][Wl-hi | Wl-lo | Wr-hi | Wr-lo][ (ks*8+ct)*64*8 + lane*8 + j ]
__global__ void k_wpack(const float* __restrict__ W0, const float* __restrict__ W1,
                        const float* __restrict__ W2, const float* __restrict__ W3,
                        const float* __restrict__ W4, const float* __restrict__ W5,
                        short* __restrict__ dst) {
    int mat = blockIdx.x >> 6;                       // 0..5 (uniform per block)
    int e = ((blockIdx.x & 63) << 8) + threadIdx.x;  // 0..16383
    const float* W = (mat == 0) ? W0 : (mat == 1) ? W1 : (mat == 2) ? W2
                   : (mat == 3) ? W3 : (mat == 4) ? W4 : W5;
    int k = e >> 7, c = e & 127;
    float w = W[e];                                  // W[k*128 + c]
    short hb = f2bf(w);
    short lb = f2bf(w - bf2f(hb));
    int ks = k >> 5, kk = k & 31, g = kk >> 3, j = kk & 7, ct = c >> 4, cl = c & 15;
    int off = ((ks * 8 + ct) * 64 + (g * 16 + cl)) * 8 + j;
    int base = (mat >> 1) * 65536 + (mat & 1) * 32768;   // layer base + Wl/Wr
    dst[base + off] = hb;
    dst[base + 16384 + off] = lb;
}

// ---------------------------------------------------------------- MFMA dual GEMM: xl = X@Wl, xr = X@Wr
// fp32 via bf16 hi/lo split: x*w = xh*wh + xh*wl + xl*wh (lo*lo dropped, ~2^-18 rel).
// Block 128 rows x 128 cols, 4 waves as 2x2, wave = 64x64 per mat.
// X staged in LDS as swizzled hi/lo bf16 [row][k] (swz on 16B slots: s ^= row&7).
// A-frag: row = lane&15, k = (lane>>4)*8+j. W read from pre-packed frags (L2-hot).
#define GB_ROWS 128
__global__ __launch_bounds__(256, 2) void k_gemm_mfma(const float* __restrict__ X,
        const short* __restrict__ Wpk,   // this layer: [Wl-hi|Wl-lo|Wr-hi|Wr-lo] x 16384
        float* __restrict__ xl, float* __restrict__ xr, int nrows) {
    __shared__ short xh[128 * 128];      // 32 KB
    __shared__ short xlo[128 * 128];     // 32 KB
    int t = threadIdx.x;
    int rowbase = blockIdx.x * GB_ROWS;

    // stage + hi/lo convert: 128 rows x 32 f4 = 4096 f4, 16 per thread
#pragma unroll
    for (int i = 0; i < 16; ++i) {
        int idx = t + i * 256;
        int r = idx >> 5;            // 0..127
        int k4 = idx & 31;           // f4 index along k
        f4 v = {0.f, 0.f, 0.f, 0.f};
        int gr = rowbase + r;
        if (gr < nrows) v = *(const f4*)&X[gr * DD + k4 * 4];
        s4 h, l;
#pragma unroll
        for (int j = 0; j < 4; ++j) {
            short hb = f2bf(v[j]);
            h[j] = hb;
            l[j] = f2bf(v[j] - bf2f(hb));
        }
        // swizzle: 16B slot s = k4>>1 -> s ^ (r&7); 8B half = k4&1
        int si = r * 128 + (((k4 >> 1) ^ (r & 7)) << 3) + (k4 & 1) * 4;
        *(s4*)&xh[si] = h;
        *(s4*)&xlo[si] = l;
    }
    __syncthreads();

    int wave = t >> 6, lane = t & 63;
    int wr = wave >> 1, wc = wave & 1;   // 2x2 wave grid

    f32x4 acc[4][4][2];
#pragma unroll
    for (int rt = 0; rt < 4; ++rt)
#pragma unroll
        for (int ct = 0; ct < 4; ++ct) {
            acc[rt][ct][0] = (f32x4){0.f, 0.f, 0.f, 0.f};
            acc[rt][ct][1] = (f32x4){0.f, 0.f, 0.f, 0.f};
        }

    for (int ks = 0; ks < 4; ++ks) {
        bf16x8 Ah[4], Al[4];
#pragma unroll
        for (int rt = 0; rt < 4; ++rt) {
            int row = wr * 64 + rt * 16 + (lane & 15);
            int slot = ks * 4 + (lane >> 4);
            int si = row * 128 + ((slot ^ (row & 7)) << 3);
            Ah[rt] = *(const bf16x8*)&xh[si];
            Al[rt] = *(const bf16x8*)&xlo[si];
        }
#pragma unroll
        for (int ct = 0; ct < 4; ++ct) {
            int ctg = wc * 4 + ct;
            int fb = ((ks * 8 + ctg) * 64 + lane) * 8;
            bf16x8 Blh = *(const bf16x8*)&Wpk[fb];
            bf16x8 Bll = *(const bf16x8*)&Wpk[16384 + fb];
            bf16x8 Brh = *(const bf16x8*)&Wpk[32768 + fb];
            bf16x8 Brl = *(const bf16x8*)&Wpk[49152 + fb];
#pragma unroll
            for (int rt = 0; rt < 4; ++rt) {
                acc[rt][ct][0] = __builtin_amdgcn_mfma_f32_16x16x32_bf16(Ah[rt], Blh, acc[rt][ct][0], 0, 0, 0);
                acc[rt][ct][0] = __builtin_amdgcn_mfma_f32_16x16x32_bf16(Ah[rt], Bll, acc[rt][ct][0], 0, 0, 0);
                acc[rt][ct][0] = __builtin_amdgcn_mfma_f32_16x16x32_bf16(Al[rt], Blh, acc[rt][ct][0], 0, 0, 0);
                acc[rt][ct][1] = __builtin_amdgcn_mfma_f32_16x16x32_bf16(Ah[rt], Brh, acc[rt][ct][1], 0, 0, 0);
                acc[rt][ct][1] = __builtin_amdgcn_mfma_f32_16x16x32_bf16(Ah[rt], Brl, acc[rt][ct][1], 0, 0, 0);
                acc[rt][ct][1] = __builtin_amdgcn_mfma_f32_16x16x32_bf16(Al[rt], Brh, acc[rt][ct][1], 0, 0, 0);
            }
        }
    }

    // epilogue: D layout col = lane&15, row = (lane>>4)*4 + reg
#pragma unroll
    for (int rt = 0; rt < 4; ++rt) {
#pragma unroll
        for (int reg = 0; reg < 4; ++reg) {
            int row = rowbase + wr * 64 + rt * 16 + (lane >> 4) * 4 + reg;
            if (row < nrows) {
#pragma unroll
                for (int ct = 0; ct < 4; ++ct) {
                    int col = wc * 64 + ct * 16 + (lane & 15);
                    xl[row * DD + col] = acc[rt][ct][0][reg];
                    xr[row * DD + col] = acc[rt][ct][1][reg];
                }
            }
        }
    }
}

// ---------------------------------------------------------------- aggregation
// Wave per node; each 16-lane QUARTER owns its own edge stream (4 edges in
// flight per wave), lane covers 8 channels. Online softmax per quarter,
// merged pairwise at the end. Next iteration's (index, weight, gather) is
// prefetched before the current compute to hide the dependent load chain.
// FUSE_FINAL: layer 3 skips writing h and directly dots with Wlin.
__device__ inline f4 lrelu4(f4 v) {
    f4 r;
    r.x = v.x > 0.f ? v.x : NEG_SLOPE * v.x;
    r.y = v.y > 0.f ? v.y : NEG_SLOPE * v.y;
    r.z = v.z > 0.f ? v.z : NEG_SLOPE * v.z;
    r.w = v.w > 0.f ? v.w : NEG_SLOPE * v.w;
    return r;
}

template<bool DO_RELU, bool FUSE_FINAL>
__global__ __launch_bounds__(256) void k_agg_t(const float* __restrict__ xl,
        const float* __restrict__ xr, const int* __restrict__ row_ptr,
        const int* __restrict__ src_sorted, const float* __restrict__ ew_sorted,
        const float* __restrict__ We, const float* __restrict__ att,
        const float* __restrict__ bias, float* __restrict__ out,
        const float* __restrict__ Wlin, const float* __restrict__ blin,
        float* __restrict__ outS) {
    int wid = (blockIdx.x * blockDim.x + threadIdx.x) >> 6;
    int lane = threadIdx.x & 63;
    if (wid >= NN) return;
    int quarter = lane >> 4;       // 0..3
    int c = (lane & 15) * 8;       // 8 channels per lane

    const f4 xrv0 = *(const f4*)&xr[wid * DD + c];
    const f4 xrv1 = *(const f4*)&xr[wid * DD + c + 4];
    const f4 att0 = *(const f4*)&att[c];
    const f4 att1 = *(const f4*)&att[c + 4];
    const f4 We0  = *(const f4*)&We[c];
    const f4 We1  = *(const f4*)&We[c + 4];

    int beg = row_ptr[wid];
    int end = row_ptr[wid + 1];
    int niter = (end - beg + 3) >> 2;

    float m = -1e30f;     // finite "minus infinity": keeps exp() NaN-free
    float d = 0.0f;
    f4 acc0 = {0,0,0,0}, acc1 = {0,0,0,0};

    // prologue: load iteration 0's edge data
    int e0 = beg + quarter;
    bool val_cur = (e0 < end);
    int ee0 = val_cur ? e0 : (end - 1);
    float w_cur = ew_sorted[ee0];
    int s_cur = src_sorted[ee0];
    f4 x0c = *(const f4*)&xl[s_cur * DD + c];
    f4 x1c = *(const f4*)&xl[s_cur * DD + c + 4];

    for (int i = 0; i < niter; ++i) {
        // prefetch iteration i+1 (independent of the softmax chain)
        f4 x0n = {0,0,0,0}, x1n = {0,0,0,0};
        float w_nxt = 0.f; bool val_nxt = false;
        if (i + 1 < niter) {
            int e = beg + 4 * (i + 1) + quarter;
            val_nxt = (e < end);
            int ee = val_nxt ? e : (end - 1);
            w_nxt = ew_sorted[ee];
            int sn = src_sorted[ee];
            x0n = *(const f4*)&xl[sn * DD + c];
            x1n = *(const f4*)&xl[sn * DD + c + 4];
        }

        f4 t0 = lrelu4(x0c + xrv0 + w_cur * We0);
        f4 t1 = lrelu4(x1c + xrv1 + w_cur * We1);
        float p = t0.x * att0.x + t0.y * att0.y + t0.z * att0.z + t0.w * att0.w
                + t1.x * att1.x + t1.y * att1.y + t1.z * att1.z + t1.w * att1.w;
#pragma unroll
        for (int o = 8; o >= 1; o >>= 1) p += __shfl_xor(p, o, 64);   // within quarter

        float logit = val_cur ? p : -1e30f;
        float nm = fmaxf(m, logit);
        float sc = __expf(m - nm);
        float pe = __expf(logit - nm);
        d = d * sc + pe;
        acc0 = acc0 * sc + pe * x0c;
        acc1 = acc1 * sc + pe * x1c;
        m = nm;

        x0c = x0n; x1c = x1n; w_cur = w_nxt; val_cur = val_nxt;
    }

    // merge the 4 quarter states (lanes l, l+16, l+32, l+48 hold same channels)
#pragma unroll
    for (int o = 16; o <= 32; o <<= 1) {
        float mo = __shfl_xor(m, o, 64);
        float dn = __shfl_xor(d, o, 64);
        f4 a0o, a1o;
        a0o.x = __shfl_xor(acc0.x, o, 64); a0o.y = __shfl_xor(acc0.y, o, 64);
        a0o.z = __shfl_xor(acc0.z, o, 64); a0o.w = __shfl_xor(acc0.w, o, 64);
        a1o.x = __shfl_xor(acc1.x, o, 64); a1o.y = __shfl_xor(acc1.y, o, 64);
        a1o.z = __shfl_xor(acc1.z, o, 64); a1o.w = __shfl_xor(acc1.w, o, 64);
        float M  = fmaxf(m, mo);
        float sA = __expf(m - M);
        float sB = __expf(mo - M);
        d = d * sA + dn * sB;
        acc0 = acc0 * sA + a0o * sB;
        acc1 = acc1 * sA + a1o * sB;
        m = M;
    }

    if (quarter == 0) {
        float inv = 1.0f / d;
        f4 bv0 = *(const f4*)&bias[c];
        f4 bv1 = *(const f4*)&bias[c + 4];
        f4 o0 = acc0 * inv + bv0;
        f4 o1 = acc1 * inv + bv1;
        if (DO_RELU) {
            o0.x = fmaxf(o0.x, 0.f); o0.y = fmaxf(o0.y, 0.f);
            o0.z = fmaxf(o0.z, 0.f); o0.w = fmaxf(o0.w, 0.f);
            o1.x = fmaxf(o1.x, 0.f); o1.y = fmaxf(o1.y, 0.f);
            o1.z = fmaxf(o1.z, 0.f); o1.w = fmaxf(o1.w, 0.f);
        }
        if (FUSE_FINAL) {
            // out[wid] = h[wid] . Wlin + blin, h never materialized
            f4 wl0 = *(const f4*)&Wlin[c];
            f4 wl1 = *(const f4*)&Wlin[c + 4];
            float p = o0.x * wl0.x + o0.y * wl0.y + o0.z * wl0.z + o0.w * wl0.w
                    + o1.x * wl1.x + o1.y * wl1.y + o1.z * wl1.z + o1.w * wl1.w;
#pragma unroll
            for (int o = 8; o >= 1; o >>= 1) p += __shfl_xor(p, o, 64);
            if (lane == 0) outS[wid] = p + blin[0];
        } else {
            *(f4*)&out[wid * DD + c] = o0;
            *(f4*)&out[wid * DD + c + 4] = o1;
        }
    }
}

// ----------------------------------------------------------------
static inline size_t align256(size_t x) { return (x + 255) & ~(size_t)255; }

extern "C" void kernel_launch(void* const* d_in, const int* in_sizes, int n_in,
                              void* d_out, int out_size, void* d_ws, size_t ws_size,
                              hipStream_t stream) {
    const float* x     = (const float*)d_in[0];
    const int*   ei    = (const int*)d_in[1];
    const float* eattr = (const float*)d_in[2];
    const float* Wl[3]  = {(const float*)d_in[3],  (const float*)d_in[8],  (const float*)d_in[13]};
    const float* Wr[3]  = {(const float*)d_in[4],  (const float*)d_in[9],  (const float*)d_in[14]};
    const float* We[3]  = {(const float*)d_in[5],  (const float*)d_in[10], (const float*)d_in[15]};
    const float* att[3] = {(const float*)d_in[6],  (const float*)d_in[11], (const float*)d_in[16]};
    const float* bb[3]  = {(const float*)d_in[7],  (const float*)d_in[12], (const float*)d_in[17]};
    const float* Wlin = (const float*)d_in[18];
    const float* blin = (const float*)d_in[19];

    char* p = (char*)d_ws;
    int* counts = (int*)p;          p += align256((size_t)NN * 4);
    int* fill   = (int*)p;          p += align256((size_t)NN * 4);
    int* row_ptr= (int*)p;          p += align256((size_t)(NN + 1) * 4);
    int* blockSums = (int*)p;       p += align256(64 * 4);
    int* blockOffs = (int*)p;       p += align256(64 * 4);
    int* src_sorted = (int*)p;      p += align256((size_t)EP * 4);
    float* ew_sorted = (float*)p;   p += align256((size_t)EP * 4);
    float* xl = (float*)p;          p += align256((size_t)NN * DD * 4);
    float* xr = (float*)p;          p += align256((size_t)NN * DD * 4);
    float* hA = (float*)p;          p += align256((size_t)NN * DD * 4);
    float* hB = (float*)p;          p += align256((size_t)NN * DD * 4);
    short* wpk = (short*)p;         p += align256((size_t)3 * 65536 * 2);  // 384 KB

    hipMemsetAsync(counts, 0, align256((size_t)NN * 4) + align256((size_t)NN * 4), stream);

    const int nb_scan = (NN + 1023) / 1024;   // 49
    k_hist<<<(EP + 255) / 256, 256, 0, stream>>>(ei, counts);
    k_scan1<<<nb_scan, 1024, 0, stream>>>(counts, row_ptr, blockSums);
    k_scan2<<<1, 64, 0, stream>>>(blockSums, blockOffs, nb_scan, row_ptr);
    k_scan3<<<nb_scan, 1024, 0, stream>>>(row_ptr, blockOffs);
    k_scatter<<<(EP + 255) / 256, 256, 0, stream>>>(ei, eattr, row_ptr, fill, src_sorted, ew_sorted);

    // pre-pack all 6 weight matrices into hi/lo bf16 MFMA fragments
    k_wpack<<<6 * 64, 256, 0, stream>>>(Wl[0], Wr[0], Wl[1], Wr[1], Wl[2], Wr[2], wpk);

    const int gemm_grid = (NN + GB_ROWS - 1) / GB_ROWS;   // 391
    const int agg_grid  = (NN + 3) / 4;                   // 4 waves per block

    // layer 1: x -> hA (relu)
    k_gemm_mfma<<<gemm_grid, 256, 0, stream>>>(x, wpk + 0 * 65536, xl, xr, NN);
    k_agg_t<true, false><<<agg_grid, 256, 0, stream>>>(xl, xr, row_ptr, src_sorted, ew_sorted,
                                        We[0], att[0], bb[0], hA, nullptr, nullptr, nullptr);
    // layer 2: hA -> hB (relu)
    k_gemm_mfma<<<gemm_grid, 256, 0, stream>>>(hA, wpk + 1 * 65536, xl, xr, NN);
    k_agg_t<true, false><<<agg_grid, 256, 0, stream>>>(xl, xr, row_ptr, src_sorted, ew_sorted,
                                        We[1], att[1], bb[1], hB, nullptr, nullptr, nullptr);
    // layer 3: hB -> (fused final linear) -> d_out
    k_gemm_mfma<<<gemm_grid, 256, 0, stream>>>(hB, wpk + 2 * 65536, xl, xr, NN);
    k_agg_t<false, true><<<agg_grid, 256, 0, stream>>>(xl, xr, row_ptr, src_sorted, ew_sorted,
                                        We[2], att[2], bb[2], nullptr, Wlin, blin, (float*)d_out);
}